// Round 1
// baseline (836.864 us; speedup 1.0000x reference)
//
#include <hip/hip_runtime.h>

constexpr int B = 64, N = 1500, NT = B * N;
constexpr int E_PER = 24000, E_TOT = B * E_PER;
constexpr int F_INN = 128, K = 30, TOT = 97, FS = 104; // FS = padded feat row stride

// ---------------- CSR build ----------------
__global__ __launch_bounds__(256) void count_deg(const int* __restrict__ dst, int* __restrict__ deg) {
    int e = blockIdx.x * 256 + threadIdx.x;
    if (e < E_TOT) atomicAdd(&deg[dst[e]], 1);
}

__global__ __launch_bounds__(256) void scan_graph(const int* __restrict__ deg, int* __restrict__ row_start,
                                                  float* __restrict__ degf) {
    __shared__ int part[256];
    int g = blockIdx.x, t = threadIdx.x;
    int base = g * N;
    int local[6];
    int sum = 0;
#pragma unroll
    for (int i = 0; i < 6; ++i) {
        int v = t * 6 + i;
        int d = (v < N) ? deg[base + v] : 0;
        local[i] = d;
        sum += d;
    }
    part[t] = sum;
    __syncthreads();
    if (t == 0) {
        int run = 0;
        for (int i = 0; i < 256; ++i) { int x = part[i]; part[i] = run; run += x; }
    }
    __syncthreads();
    int run = part[t];
#pragma unroll
    for (int i = 0; i < 6; ++i) {
        int v = t * 6 + i;
        if (v < N) {
            row_start[base + v] = g * E_PER + run;
            degf[base + v] = (float)(local[i] + 1);
            run += local[i];
        }
    }
}

__global__ __launch_bounds__(256) void scatter_edges(const int* __restrict__ src, const int* __restrict__ dst,
                                                     const int* __restrict__ row_start, int* __restrict__ cursor,
                                                     int* __restrict__ csr) {
    int e = blockIdx.x * 256 + threadIdx.x;
    if (e < E_TOT) {
        int d = dst[e];
        int pos = row_start[d] + atomicAdd(&cursor[d], 1);
        csr[pos] = src[e];
    }
}

// ---------------- Layer 1: 128 -> 32 ----------------
__global__ __launch_bounds__(256) void layer1(const float* __restrict__ h,
                                              const int* __restrict__ csr, const int* __restrict__ row_start,
                                              const int* __restrict__ degi, const float* __restrict__ degf,
                                              const float* __restrict__ W, const float* __restrict__ bias,
                                              float* __restrict__ feat) {
    __shared__ float Wl[F_INN * 32];
    __shared__ float aggl[4][F_INN];
    for (int i = threadIdx.x; i < F_INN * 32; i += 256) Wl[i] = W[i];
    __syncthreads();
    int wave = threadIdx.x >> 6, lane = threadIdx.x & 63;
    int gw = blockIdx.x * 4 + wave;
    int nw = gridDim.x * 4;
    int iters = (NT + nw - 1) / nw;
    for (int it = 0; it < iters; ++it) {
        int v = gw + it * nw;
        if (v < NT) {
            int e0 = row_start[v];
            int dcnt = degi[v];
            float a0 = h[v * F_INN + lane];
            float a1 = h[v * F_INN + lane + 64];
            for (int e = 0; e < dcnt; ++e) {
                int s = csr[e0 + e];
                a0 += h[s * F_INN + lane];
                a1 += h[s * F_INN + lane + 64];
            }
            aggl[wave][lane] = a0;
            aggl[wave][lane + 64] = a1;
        }
        __syncthreads();
        if (v < NT && lane < 32) {
            float acc = bias[lane];
            float inv = 1.0f / degf[v];
#pragma unroll 8
            for (int f = 0; f < F_INN; ++f)
                acc += aggl[wave][f] * Wl[f * 32 + lane];
            feat[(size_t)v * FS + lane] = tanhf(acc * inv);
        }
        __syncthreads();
    }
}

// ---------------- Layers 2..4: 32 -> F_OUT (32 or 1) ----------------
template <int IN_OFF, int OUT_OFF, int F_OUT>
__global__ __launch_bounds__(256) void layerN(const int* __restrict__ csr, const int* __restrict__ row_start,
                                              const int* __restrict__ degi, const float* __restrict__ degf,
                                              const float* __restrict__ W, const float* __restrict__ bias,
                                              float* __restrict__ feat) {
    __shared__ float Wl[32 * F_OUT];
    for (int i = threadIdx.x; i < 32 * F_OUT; i += 256) Wl[i] = W[i];
    __syncthreads();
    int wave = threadIdx.x >> 6, lane = threadIdx.x & 63;
    int half = lane >> 5, f = lane & 31;
    int gw = blockIdx.x * 4 + wave;
    int nw = gridDim.x * 4;
    int npair = NT / 2;
    for (int p = gw; p < npair; p += nw) {
        int v = p * 2 + half;
        int e0 = row_start[v];
        int dcnt = degi[v];
        float a = feat[(size_t)v * FS + IN_OFF + f];
        for (int e = 0; e < dcnt; ++e) {
            int s = csr[e0 + e];
            a += feat[(size_t)s * FS + IN_OFF + f];
        }
        if (F_OUT == 32) {
            float acc = bias[f];
#pragma unroll
            for (int ff = 0; ff < 32; ++ff) {
                float af = __shfl(a, half * 32 + ff, 64);
                acc += af * Wl[ff * 32 + f];
            }
            feat[(size_t)v * FS + OUT_OFF + f] = tanhf(acc / degf[v]);
        } else {
            float partial = a * Wl[f];
#pragma unroll
            for (int m = 16; m >= 1; m >>= 1)
                partial += __shfl_xor(partial, m, 64);
            if (f == 0)
                feat[(size_t)v * FS + OUT_OFF] = tanhf((partial + bias[0]) / degf[v]);
        }
    }
}

// ---------------- Sortpool: top-K per graph by last channel ----------------
__global__ __launch_bounds__(256) void sortpool(const float* __restrict__ feat, int* __restrict__ gidx) {
    __shared__ float vals[N];
    __shared__ float rbest[256];
    __shared__ int ribest[256];
    int g = blockIdx.x, t = threadIdx.x;
    for (int v = t; v < N; v += 256) vals[v] = feat[(size_t)(g * N + v) * FS + 96];
    __syncthreads();
    for (int k = 0; k < K; ++k) {
        float bv = -1e30f;
        int bi = N;
        for (int v = t; v < N; v += 256) {
            float x = vals[v];
            if (x > bv) { bv = x; bi = v; }
        }
        rbest[t] = bv; ribest[t] = bi;
        __syncthreads();
        for (int s = 128; s >= 1; s >>= 1) {
            if (t < s) {
                float ov = rbest[t + s]; int oi = ribest[t + s];
                if (ov > rbest[t] || (ov == rbest[t] && oi < ribest[t])) { rbest[t] = ov; ribest[t] = oi; }
            }
            __syncthreads();
        }
        if (t == 0) {
            gidx[g * K + k] = g * N + ribest[0];
            vals[ribest[0]] = -1e30f;
        }
        __syncthreads();
    }
}

// ---------------- Head: conv1 + maxpool + conv2 + dense ----------------
__global__ __launch_bounds__(256) void head(const float* __restrict__ feat, const int* __restrict__ gidx,
                                            const float* __restrict__ c1w, const float* __restrict__ c1b,
                                            const float* __restrict__ c2w, const float* __restrict__ c2b,
                                            const float* __restrict__ ow, const float* __restrict__ ob,
                                            float* __restrict__ out) {
    __shared__ float pooled[K][TOT];
    __shared__ float c1[16][K];
    __shared__ float mp[16][16];
    __shared__ float dense[352];
    int g = blockIdx.x, t = threadIdx.x;
    for (int i = t; i < K * TOT; i += 256) {
        int k = i / TOT, d = i % TOT;
        pooled[k][d] = feat[(size_t)gidx[g * K + k] * FS + d];
    }
    __syncthreads();
    for (int i = t; i < 16 * K; i += 256) {
        int o = i / K, k = i % K;
        float s = c1b[o];
        for (int d = 0; d < TOT; ++d) s += pooled[k][d] * c1w[o * TOT + d];
        c1[o][k] = fmaxf(s, 0.f);
    }
    __syncthreads();
    for (int i = t; i < 16 * 15; i += 256) {
        int o = i / 15, p = i % 15;
        mp[o][p] = fmaxf(c1[o][2 * p], c1[o][2 * p + 1]);
    }
    __syncthreads();
    for (int i = t; i < 352; i += 256) {
        int o = i / 11, p = i % 11;
        float s = c2b[o];
#pragma unroll
        for (int ci = 0; ci < 16; ++ci)
#pragma unroll
            for (int tt = 0; tt < 5; ++tt)
                s += mp[ci][p + tt] * c2w[(o * 16 + ci) * 5 + tt];
        dense[i] = fmaxf(s, 0.f);
    }
    __syncthreads();
    if (t < 128) {
        float s = ob[t];
        for (int m = 0; m < 352; ++m) s += dense[m] * ow[m * 128 + t];
        out[g * 128 + t] = fmaxf(s, 0.f);
    }
}

extern "C" void kernel_launch(void* const* d_in, const int* in_sizes, int n_in,
                              void* d_out, int out_size, void* d_ws, size_t ws_size,
                              hipStream_t stream) {
    const float* node_feat = (const float*)d_in[0];
    const int* esrc = (const int*)d_in[1];
    const int* edst = (const int*)d_in[2];
    const float* W1 = (const float*)d_in[3];
    const float* b1 = (const float*)d_in[4];
    const float* W2 = (const float*)d_in[5];
    const float* b2 = (const float*)d_in[6];
    const float* W3 = (const float*)d_in[7];
    const float* b3 = (const float*)d_in[8];
    const float* W4 = (const float*)d_in[9];
    const float* b4 = (const float*)d_in[10];
    const float* c1w = (const float*)d_in[11];
    const float* c1b = (const float*)d_in[12];
    const float* c2w = (const float*)d_in[13];
    const float* c2b = (const float*)d_in[14];
    const float* ow = (const float*)d_in[15];
    const float* ob = (const float*)d_in[16];

    char* ws = (char*)d_ws;
    size_t off = 0;
    auto alloc = [&](size_t bytes) {
        size_t r = off;
        off += (bytes + 255) & ~(size_t)255;
        return r;
    };
    int* deg_i = (int*)(ws + alloc((size_t)NT * 4));
    int* cursor = (int*)(ws + alloc((size_t)NT * 4));
    int* rowst = (int*)(ws + alloc((size_t)NT * 4));
    float* degf = (float*)(ws + alloc((size_t)NT * 4));
    int* csr = (int*)(ws + alloc((size_t)E_TOT * 4));
    int* gidx = (int*)(ws + alloc((size_t)B * K * 4));
    float* feat = (float*)(ws + alloc((size_t)NT * FS * 4));

    // deg_i and cursor are adjacent (NT*4 = 384000 is 256-aligned): one memset
    hipMemsetAsync(deg_i, 0, (size_t)NT * 4 * 2, stream);
    count_deg<<<(E_TOT + 255) / 256, 256, 0, stream>>>(edst, deg_i);
    scan_graph<<<B, 256, 0, stream>>>(deg_i, rowst, degf);
    scatter_edges<<<(E_TOT + 255) / 256, 256, 0, stream>>>(esrc, edst, rowst, cursor, csr);
    layer1<<<1024, 256, 0, stream>>>(node_feat, csr, rowst, deg_i, degf, W1, b1, feat);
    layerN<0, 32, 32><<<1024, 256, 0, stream>>>(csr, rowst, deg_i, degf, W2, b2, feat);
    layerN<32, 64, 32><<<1024, 256, 0, stream>>>(csr, rowst, deg_i, degf, W3, b3, feat);
    layerN<64, 96, 1><<<1024, 256, 0, stream>>>(csr, rowst, deg_i, degf, W4, b4, feat);
    sortpool<<<B, 256, 0, stream>>>(feat, gidx);
    head<<<B, 256, 0, stream>>>(feat, gidx, c1w, c1b, c2w, c2b, ow, ob, (float*)d_out);
}

// Round 2
// 455.969 us; speedup vs baseline: 1.8354x; 1.8354x over previous
//
#include <hip/hip_runtime.h>

constexpr int B = 64, N = 1500, NT = B * N;
constexpr int E_PER = 24000, E_TOT = B * E_PER;
constexpr int F_INN = 128, K = 30, TOT = 97, FS = 100; // FS = feat row stride

// ---------------- CSR build ----------------
__global__ __launch_bounds__(256) void count_deg(const int* __restrict__ dst, int* __restrict__ deg) {
    int e = blockIdx.x * 256 + threadIdx.x;
    if (e < E_TOT) atomicAdd(&deg[dst[e]], 1);
}

__global__ __launch_bounds__(256) void scan_graph(const int* __restrict__ deg, int* __restrict__ row_start,
                                                  float* __restrict__ degf) {
    __shared__ int part[256];
    int g = blockIdx.x, t = threadIdx.x;
    int base = g * N;
    int local[6];
    int sum = 0;
#pragma unroll
    for (int i = 0; i < 6; ++i) {
        int v = t * 6 + i;
        int d = (v < N) ? deg[base + v] : 0;
        local[i] = d;
        sum += d;
    }
    part[t] = sum;
    __syncthreads();
    if (t == 0) {
        int run = 0;
        for (int i = 0; i < 256; ++i) { int x = part[i]; part[i] = run; run += x; }
    }
    __syncthreads();
    int run = part[t];
#pragma unroll
    for (int i = 0; i < 6; ++i) {
        int v = t * 6 + i;
        if (v < N) {
            row_start[base + v] = g * E_PER + run;
            degf[base + v] = (float)(local[i] + 1);
            run += local[i];
        }
    }
}

__global__ __launch_bounds__(256) void scatter_edges(const int* __restrict__ src, const int* __restrict__ dst,
                                                     const int* __restrict__ row_start, int* __restrict__ cursor,
                                                     int* __restrict__ csr) {
    int e = blockIdx.x * 256 + threadIdx.x;
    if (e < E_TOT) {
        int d = dst[e];
        int pos = row_start[d] + atomicAdd(&cursor[d], 1);
        csr[pos] = src[e];
    }
}

// ---------------- Transform: t1 = node_feat @ W1  (128 -> 32) ----------------
__global__ __launch_bounds__(256) void transform1(const float* __restrict__ h,
                                                  const float* __restrict__ W,
                                                  float* __restrict__ t1) {
    __shared__ float Wl[F_INN * 32];
    for (int i = threadIdx.x; i < F_INN * 32; i += 256) Wl[i] = W[i];
    __syncthreads();
    int v = blockIdx.x * 8 + (threadIdx.x >> 5);
    int f = threadIdx.x & 31;
    int base = threadIdx.x & 32;
    float4 hv = reinterpret_cast<const float4*>(h + (size_t)v * F_INN)[f];
    float acc = 0.f;
#pragma unroll
    for (int ff = 0; ff < 32; ++ff) {
        float x = __shfl(hv.x, base + ff, 64);
        float y = __shfl(hv.y, base + ff, 64);
        float z = __shfl(hv.z, base + ff, 64);
        float w = __shfl(hv.w, base + ff, 64);
        acc += x * Wl[(4 * ff + 0) * 32 + f];
        acc += y * Wl[(4 * ff + 1) * 32 + f];
        acc += z * Wl[(4 * ff + 2) * 32 + f];
        acc += w * Wl[(4 * ff + 3) * 32 + f];
    }
    t1[(size_t)v * 32 + f] = acc;
}

// ---------------- Aggregate (+optional GEMV) per node, half-wave per node ----
// MODE 0: out_f = tanh((gather_f + b_f)/deg)                 (layer1, input pre-transformed)
// MODE 1: z = gather @ W (32x32 via shuffles), out = tanh((z+b)/deg)
// MODE 2: z = gather . W (32->1), out scalar
template <int MODE, int OUT_OFF>
__global__ __launch_bounds__(256) void agg_k(const float* __restrict__ tin, int in_stride, int in_off,
                                             const int* __restrict__ csr, const int* __restrict__ rowst,
                                             const int* __restrict__ degi, const float* __restrict__ degf,
                                             const float* __restrict__ W, const float* __restrict__ bias,
                                             float* __restrict__ feat) {
    __shared__ float Wl[1024];
    if (MODE == 1) {
        for (int i = threadIdx.x; i < 1024; i += 256) Wl[i] = W[i];
        __syncthreads();
    }
    int v = blockIdx.x * 8 + (threadIdx.x >> 5);
    int f = threadIdx.x & 31;
    const float* tp = tin + in_off + f;
    float acc = tp[(size_t)v * in_stride];
    int e0 = rowst[v], dc = degi[v];
    float a0 = 0.f, a1 = 0.f, a2 = 0.f, a3 = 0.f;
    int e = 0;
    for (; e + 4 <= dc; e += 4) {
        int s0 = csr[e0 + e], s1 = csr[e0 + e + 1], s2 = csr[e0 + e + 2], s3 = csr[e0 + e + 3];
        a0 += tp[(size_t)s0 * in_stride];
        a1 += tp[(size_t)s1 * in_stride];
        a2 += tp[(size_t)s2 * in_stride];
        a3 += tp[(size_t)s3 * in_stride];
    }
    for (; e < dc; ++e) a0 += tp[(size_t)csr[e0 + e] * in_stride];
    acc += (a0 + a1) + (a2 + a3);
    float inv = 1.0f / degf[v];
    if (MODE == 0) {
        feat[(size_t)v * FS + OUT_OFF + f] = tanhf((acc + bias[f]) * inv);
    } else if (MODE == 1) {
        float z = 0.f;
        int base = threadIdx.x & 32;
#pragma unroll
        for (int ff = 0; ff < 32; ++ff)
            z += __shfl(acc, base + ff, 64) * Wl[ff * 32 + f];
        feat[(size_t)v * FS + OUT_OFF + f] = tanhf((z + bias[f]) * inv);
    } else {
        float p = acc * W[f];
#pragma unroll
        for (int m = 16; m >= 1; m >>= 1) p += __shfl_xor(p, m, 64);
        if (f == 0) feat[(size_t)v * FS + OUT_OFF] = tanhf((p + bias[0]) * inv);
    }
}

// ---------------- Sortpool: top-K per graph by last channel ----------------
__global__ __launch_bounds__(256) void sortpool(const float* __restrict__ feat, int* __restrict__ gidx) {
    __shared__ float vals[N];
    __shared__ float wv[4];
    __shared__ int wi[4];
    int g = blockIdx.x, t = threadIdx.x;
    int lane = t & 63, wave = t >> 6;
    for (int v = t; v < N; v += 256) vals[v] = feat[(size_t)(g * N + v) * FS + 96];
    __syncthreads();
    for (int k = 0; k < K; ++k) {
        float bv = -1e30f;
        int bi = N;
        for (int v = t; v < N; v += 256) {
            float x = vals[v];
            if (x > bv) { bv = x; bi = v; }
        }
#pragma unroll
        for (int m = 32; m >= 1; m >>= 1) {
            float ov = __shfl_xor(bv, m, 64);
            int oi = __shfl_xor(bi, m, 64);
            if (ov > bv || (ov == bv && oi < bi)) { bv = ov; bi = oi; }
        }
        if (lane == 0) { wv[wave] = bv; wi[wave] = bi; }
        __syncthreads();
        if (t == 0) {
            float b0 = wv[0];
            int i0 = wi[0];
            for (int w = 1; w < 4; ++w)
                if (wv[w] > b0 || (wv[w] == b0 && wi[w] < i0)) { b0 = wv[w]; i0 = wi[w]; }
            gidx[g * K + k] = g * N + i0;
            vals[i0] = -1e30f;
        }
        __syncthreads();
    }
}

// ---------------- Head: conv1 + maxpool + conv2 + dense ----------------
__global__ __launch_bounds__(256) void head(const float* __restrict__ feat, const int* __restrict__ gidx,
                                            const float* __restrict__ c1w, const float* __restrict__ c1b,
                                            const float* __restrict__ c2w, const float* __restrict__ c2b,
                                            const float* __restrict__ ow, const float* __restrict__ ob,
                                            float* __restrict__ out) {
    __shared__ float pooled[K][TOT];
    __shared__ float c1[16][K];
    __shared__ float mp[16][16];
    __shared__ float dense[352];
    int g = blockIdx.x, t = threadIdx.x;
    for (int i = t; i < K * TOT; i += 256) {
        int k = i / TOT, d = i % TOT;
        pooled[k][d] = feat[(size_t)gidx[g * K + k] * FS + d];
    }
    __syncthreads();
    for (int i = t; i < 16 * K; i += 256) {
        int o = i / K, k = i % K;
        float s = c1b[o];
        for (int d = 0; d < TOT; ++d) s += pooled[k][d] * c1w[o * TOT + d];
        c1[o][k] = fmaxf(s, 0.f);
    }
    __syncthreads();
    for (int i = t; i < 16 * 15; i += 256) {
        int o = i / 15, p = i % 15;
        mp[o][p] = fmaxf(c1[o][2 * p], c1[o][2 * p + 1]);
    }
    __syncthreads();
    for (int i = t; i < 352; i += 256) {
        int o = i / 11, p = i % 11;
        float s = c2b[o];
#pragma unroll
        for (int ci = 0; ci < 16; ++ci)
#pragma unroll
            for (int tt = 0; tt < 5; ++tt)
                s += mp[ci][p + tt] * c2w[(o * 16 + ci) * 5 + tt];
        dense[i] = fmaxf(s, 0.f);
    }
    __syncthreads();
    if (t < 128) {
        float s = ob[t];
        for (int m = 0; m < 352; ++m) s += dense[m] * ow[m * 128 + t];
        out[g * 128 + t] = fmaxf(s, 0.f);
    }
}

extern "C" void kernel_launch(void* const* d_in, const int* in_sizes, int n_in,
                              void* d_out, int out_size, void* d_ws, size_t ws_size,
                              hipStream_t stream) {
    const float* node_feat = (const float*)d_in[0];
    const int* esrc = (const int*)d_in[1];
    const int* edst = (const int*)d_in[2];
    const float* W1 = (const float*)d_in[3];
    const float* b1 = (const float*)d_in[4];
    const float* W2 = (const float*)d_in[5];
    const float* b2 = (const float*)d_in[6];
    const float* W3 = (const float*)d_in[7];
    const float* b3 = (const float*)d_in[8];
    const float* W4 = (const float*)d_in[9];
    const float* b4 = (const float*)d_in[10];
    const float* c1w = (const float*)d_in[11];
    const float* c1b = (const float*)d_in[12];
    const float* c2w = (const float*)d_in[13];
    const float* c2b = (const float*)d_in[14];
    const float* ow = (const float*)d_in[15];
    const float* ob = (const float*)d_in[16];

    char* ws = (char*)d_ws;
    size_t off = 0;
    auto alloc = [&](size_t bytes) {
        size_t r = off;
        off += (bytes + 255) & ~(size_t)255;
        return r;
    };
    int* deg_i = (int*)(ws + alloc((size_t)NT * 4));
    int* cursor = (int*)(ws + alloc((size_t)NT * 4));
    int* rowst = (int*)(ws + alloc((size_t)NT * 4));
    float* degf = (float*)(ws + alloc((size_t)NT * 4));
    int* csr = (int*)(ws + alloc((size_t)E_TOT * 4));
    int* gidx = (int*)(ws + alloc((size_t)B * K * 4));
    float* t1 = (float*)(ws + alloc((size_t)NT * 32 * 4));
    float* feat = (float*)(ws + alloc((size_t)NT * FS * 4));

    // deg_i and cursor are adjacent (NT*4 is 256-aligned): one memset clears both
    hipMemsetAsync(deg_i, 0, (size_t)NT * 4 * 2, stream);
    count_deg<<<(E_TOT + 255) / 256, 256, 0, stream>>>(edst, deg_i);
    scan_graph<<<B, 256, 0, stream>>>(deg_i, rowst, degf);
    scatter_edges<<<(E_TOT + 255) / 256, 256, 0, stream>>>(esrc, edst, rowst, cursor, csr);

    transform1<<<NT / 8, 256, 0, stream>>>(node_feat, W1, t1);
    agg_k<0, 0><<<NT / 8, 256, 0, stream>>>(t1, 32, 0, csr, rowst, deg_i, degf, nullptr, b1, feat);
    agg_k<1, 32><<<NT / 8, 256, 0, stream>>>(feat, FS, 0, csr, rowst, deg_i, degf, W2, b2, feat);
    agg_k<1, 64><<<NT / 8, 256, 0, stream>>>(feat, FS, 32, csr, rowst, deg_i, degf, W3, b3, feat);
    agg_k<2, 96><<<NT / 8, 256, 0, stream>>>(feat, FS, 64, csr, rowst, deg_i, degf, W4, b4, feat);

    sortpool<<<B, 256, 0, stream>>>(feat, gidx);
    head<<<B, 256, 0, stream>>>(feat, gidx, c1w, c1b, c2w, c2b, ow, ob, (float*)d_out);
}

// Round 3
// 337.013 us; speedup vs baseline: 2.4832x; 1.3530x over previous
//
#include <hip/hip_runtime.h>

constexpr int B = 64, N = 1500, NT = B * N;
constexpr int E_PER = 24000, E_TOT = B * E_PER;
constexpr int F_INN = 128, K = 30, TOT = 97;

// ---------------- CSR build ----------------
__global__ __launch_bounds__(256) void count_deg(const int* __restrict__ dst, int* __restrict__ deg) {
    int e = blockIdx.x * 256 + threadIdx.x;
    if (e < E_TOT) atomicAdd(&deg[dst[e]], 1);
}

__global__ __launch_bounds__(256) void scan_graph(const int* __restrict__ deg, int* __restrict__ row_start,
                                                  float* __restrict__ degf) {
    __shared__ int part[256];
    int g = blockIdx.x, t = threadIdx.x;
    int base = g * N;
    int local[6];
    int sum = 0;
#pragma unroll
    for (int i = 0; i < 6; ++i) {
        int v = t * 6 + i;
        int d = (v < N) ? deg[base + v] : 0;
        local[i] = d;
        sum += d;
    }
    part[t] = sum;
    __syncthreads();
    if (t == 0) {
        int run = 0;
        for (int i = 0; i < 256; ++i) { int x = part[i]; part[i] = run; run += x; }
    }
    __syncthreads();
    int run = part[t];
#pragma unroll
    for (int i = 0; i < 6; ++i) {
        int v = t * 6 + i;
        if (v < N) {
            row_start[base + v] = g * E_PER + run;
            degf[base + v] = (float)(local[i] + 1);
            run += local[i];
        }
    }
}

__global__ __launch_bounds__(256) void scatter_edges(const int* __restrict__ src, const int* __restrict__ dst,
                                                     const int* __restrict__ row_start, int* __restrict__ cursor,
                                                     int* __restrict__ csr) {
    int e = blockIdx.x * 256 + threadIdx.x;
    if (e < E_TOT) {
        int d = dst[e];
        int pos = row_start[d] + atomicAdd(&cursor[d], 1);
        csr[pos] = src[e];
    }
}

// ---------------- Tiled GEMM: t[NT,32] = h[NT,KDIM] @ W[KDIM,32] ----------------
// 128 nodes per block; wave w owns output cols [8w,8w+8); lane owns nodes {2l, 2l+1}.
template <int KDIM>
__global__ __launch_bounds__(256) void gemm_t(const float* __restrict__ h,
                                              const float* __restrict__ W,
                                              float* __restrict__ t) {
    __shared__ float hs[32][128]; // [k][node] transposed chunk
    __shared__ float Ws[32][32];  // [k][out] chunk
    int tid = threadIdx.x;
    int wv = tid >> 6, lane = tid & 63;
    int v0 = blockIdx.x * 128;
    int og = wv * 8;
    float acc[2][8];
#pragma unroll
    for (int i = 0; i < 2; ++i)
#pragma unroll
        for (int j = 0; j < 8; ++j) acc[i][j] = 0.f;

    for (int kc = 0; kc < KDIM; kc += 32) {
        __syncthreads();
        { // stage h chunk transposed: thread covers node (tid>>1), k-half (tid&1)*16
            int n = tid >> 1, kh = (tid & 1) * 16;
            const float* hp = h + (size_t)(v0 + n) * KDIM + kc + kh;
            const float4* hp4 = reinterpret_cast<const float4*>(hp);
            float4 a = hp4[0], b = hp4[1], c = hp4[2], d = hp4[3];
            hs[kh + 0][n] = a.x;  hs[kh + 1][n] = a.y;  hs[kh + 2][n] = a.z;  hs[kh + 3][n] = a.w;
            hs[kh + 4][n] = b.x;  hs[kh + 5][n] = b.y;  hs[kh + 6][n] = b.z;  hs[kh + 7][n] = b.w;
            hs[kh + 8][n] = c.x;  hs[kh + 9][n] = c.y;  hs[kh + 10][n] = c.z; hs[kh + 11][n] = c.w;
            hs[kh + 12][n] = d.x; hs[kh + 13][n] = d.y; hs[kh + 14][n] = d.z; hs[kh + 15][n] = d.w;
        }
        { // stage W chunk: 32 rows x 32 cols, thread loads one float4
            int r = tid >> 3, c4 = (tid & 7) * 4;
            float4 w = *reinterpret_cast<const float4*>(W + (size_t)(kc + r) * 32 + c4);
            *reinterpret_cast<float4*>(&Ws[r][c4]) = w;
        }
        __syncthreads();
#pragma unroll
        for (int k = 0; k < 32; ++k) {
            float2 hv = *reinterpret_cast<const float2*>(&hs[k][2 * lane]);
            float4 w0 = *reinterpret_cast<const float4*>(&Ws[k][og]);
            float4 w1 = *reinterpret_cast<const float4*>(&Ws[k][og + 4]);
            acc[0][0] += hv.x * w0.x; acc[0][1] += hv.x * w0.y; acc[0][2] += hv.x * w0.z; acc[0][3] += hv.x * w0.w;
            acc[0][4] += hv.x * w1.x; acc[0][5] += hv.x * w1.y; acc[0][6] += hv.x * w1.z; acc[0][7] += hv.x * w1.w;
            acc[1][0] += hv.y * w0.x; acc[1][1] += hv.y * w0.y; acc[1][2] += hv.y * w0.z; acc[1][3] += hv.y * w0.w;
            acc[1][4] += hv.y * w1.x; acc[1][5] += hv.y * w1.y; acc[1][6] += hv.y * w1.z; acc[1][7] += hv.y * w1.w;
        }
    }
#pragma unroll
    for (int i = 0; i < 2; ++i) {
        float* op = t + (size_t)(v0 + 2 * lane + i) * 32 + og;
        float4 r0 = {acc[i][0], acc[i][1], acc[i][2], acc[i][3]};
        float4 r1 = {acc[i][4], acc[i][5], acc[i][6], acc[i][7]};
        reinterpret_cast<float4*>(op)[0] = r0;
        reinterpret_cast<float4*>(op)[1] = r1;
    }
}

// ---------------- Aggregate 32-wide: hout = tanh((gather(t)+t_self+b)/deg) ------
// half-wave per node; optional fused layer-4 transform (32->1 reduce) epilogue
template <bool DO_T4>
__global__ __launch_bounds__(256) void agg32(const float* __restrict__ t,
                                             const int* __restrict__ csr, const int* __restrict__ rowst,
                                             const int* __restrict__ degi, const float* __restrict__ degf,
                                             const float* __restrict__ bias, const float* __restrict__ W4,
                                             float* __restrict__ hout, float* __restrict__ t4) {
    int v = blockIdx.x * 8 + (threadIdx.x >> 5);
    int f = threadIdx.x & 31;
    const float* tp = t + f;
    float acc = tp[(size_t)v * 32];
    int e0 = rowst[v], dc = degi[v];
    float a0 = 0.f, a1 = 0.f, a2 = 0.f, a3 = 0.f;
    int e = 0;
    for (; e + 4 <= dc; e += 4) {
        int s0 = csr[e0 + e], s1 = csr[e0 + e + 1], s2 = csr[e0 + e + 2], s3 = csr[e0 + e + 3];
        a0 += tp[(size_t)s0 * 32];
        a1 += tp[(size_t)s1 * 32];
        a2 += tp[(size_t)s2 * 32];
        a3 += tp[(size_t)s3 * 32];
    }
    for (; e < dc; ++e) a0 += tp[(size_t)csr[e0 + e] * 32];
    acc += (a0 + a1) + (a2 + a3);
    float out = tanhf((acc + bias[f]) / degf[v]);
    hout[(size_t)v * 32 + f] = out;
    if (DO_T4) {
        float p = out * W4[f];
#pragma unroll
        for (int m = 16; m >= 1; m >>= 1) p += __shfl_xor(p, m, 64);
        if (f == 0) t4[v] = p;
    }
}

// ---------------- Layer-4 aggregate: scalar gather ----------------
__global__ __launch_bounds__(256) void agg1f(const float* __restrict__ t4,
                                             const int* __restrict__ csr, const int* __restrict__ rowst,
                                             const int* __restrict__ degi, const float* __restrict__ degf,
                                             const float* __restrict__ b4, float* __restrict__ h4) {
    int v = blockIdx.x * 256 + threadIdx.x;
    if (v >= NT) return;
    float acc = t4[v];
    int e0 = rowst[v], dc = degi[v];
    float a0 = 0.f, a1 = 0.f, a2 = 0.f, a3 = 0.f;
    int e = 0;
    for (; e + 4 <= dc; e += 4) {
        a0 += t4[csr[e0 + e]];
        a1 += t4[csr[e0 + e + 1]];
        a2 += t4[csr[e0 + e + 2]];
        a3 += t4[csr[e0 + e + 3]];
    }
    for (; e < dc; ++e) a0 += t4[csr[e0 + e]];
    acc += (a0 + a1) + (a2 + a3);
    h4[v] = tanhf((acc + b4[0]) / degf[v]);
}

// ---------------- Sortpool: top-K per graph by h4 ----------------
__global__ __launch_bounds__(256) void sortpool(const float* __restrict__ h4, int* __restrict__ gidx) {
    __shared__ float vals[N];
    __shared__ float wv[4];
    __shared__ int wi[4];
    int g = blockIdx.x, t = threadIdx.x;
    int lane = t & 63, wave = t >> 6;
    for (int v = t; v < N; v += 256) vals[v] = h4[g * N + v];
    __syncthreads();
    for (int k = 0; k < K; ++k) {
        float bv = -1e30f;
        int bi = N;
        for (int v = t; v < N; v += 256) {
            float x = vals[v];
            if (x > bv) { bv = x; bi = v; }
        }
#pragma unroll
        for (int m = 32; m >= 1; m >>= 1) {
            float ov = __shfl_xor(bv, m, 64);
            int oi = __shfl_xor(bi, m, 64);
            if (ov > bv || (ov == bv && oi < bi)) { bv = ov; bi = oi; }
        }
        if (lane == 0) { wv[wave] = bv; wi[wave] = bi; }
        __syncthreads();
        if (t == 0) {
            float b0 = wv[0];
            int i0 = wi[0];
            for (int w = 1; w < 4; ++w)
                if (wv[w] > b0 || (wv[w] == b0 && wi[w] < i0)) { b0 = wv[w]; i0 = wi[w]; }
            gidx[g * K + k] = g * N + i0;
            vals[i0] = -1e30f;
        }
        __syncthreads();
    }
}

// ---------------- Head: conv1 + maxpool + conv2 + dense ----------------
__global__ __launch_bounds__(256) void head(const float* __restrict__ hc1, const float* __restrict__ hc2,
                                            const float* __restrict__ hc3, const float* __restrict__ h4,
                                            const int* __restrict__ gidx,
                                            const float* __restrict__ c1w, const float* __restrict__ c1b,
                                            const float* __restrict__ c2w, const float* __restrict__ c2b,
                                            const float* __restrict__ ow, const float* __restrict__ ob,
                                            float* __restrict__ out) {
    __shared__ float pooled[K][TOT];
    __shared__ float c1[16][K];
    __shared__ float mp[16][16];
    __shared__ float dense[352];
    int g = blockIdx.x, t = threadIdx.x;
    for (int i = t; i < K * TOT; i += 256) {
        int k = i / TOT, d = i % TOT;
        int gi = gidx[g * K + k];
        float val = (d < 32) ? hc1[(size_t)gi * 32 + d]
                  : (d < 64) ? hc2[(size_t)gi * 32 + d - 32]
                  : (d < 96) ? hc3[(size_t)gi * 32 + d - 64]
                             : h4[gi];
        pooled[k][d] = val;
    }
    __syncthreads();
    for (int i = t; i < 16 * K; i += 256) {
        int o = i / K, k = i % K;
        float s = c1b[o];
        for (int d = 0; d < TOT; ++d) s += pooled[k][d] * c1w[o * TOT + d];
        c1[o][k] = fmaxf(s, 0.f);
    }
    __syncthreads();
    for (int i = t; i < 16 * 15; i += 256) {
        int o = i / 15, p = i % 15;
        mp[o][p] = fmaxf(c1[o][2 * p], c1[o][2 * p + 1]);
    }
    __syncthreads();
    for (int i = t; i < 352; i += 256) {
        int o = i / 11, p = i % 11;
        float s = c2b[o];
#pragma unroll
        for (int ci = 0; ci < 16; ++ci)
#pragma unroll
            for (int tt = 0; tt < 5; ++tt)
                s += mp[ci][p + tt] * c2w[(o * 16 + ci) * 5 + tt];
        dense[i] = fmaxf(s, 0.f);
    }
    __syncthreads();
    if (t < 128) {
        float s = ob[t];
        for (int m = 0; m < 352; ++m) s += dense[m] * ow[m * 128 + t];
        out[g * 128 + t] = fmaxf(s, 0.f);
    }
}

extern "C" void kernel_launch(void* const* d_in, const int* in_sizes, int n_in,
                              void* d_out, int out_size, void* d_ws, size_t ws_size,
                              hipStream_t stream) {
    const float* node_feat = (const float*)d_in[0];
    const int* esrc = (const int*)d_in[1];
    const int* edst = (const int*)d_in[2];
    const float* W1 = (const float*)d_in[3];
    const float* b1 = (const float*)d_in[4];
    const float* W2 = (const float*)d_in[5];
    const float* b2 = (const float*)d_in[6];
    const float* W3 = (const float*)d_in[7];
    const float* b3 = (const float*)d_in[8];
    const float* W4 = (const float*)d_in[9];
    const float* b4 = (const float*)d_in[10];
    const float* c1w = (const float*)d_in[11];
    const float* c1b = (const float*)d_in[12];
    const float* c2w = (const float*)d_in[13];
    const float* c2b = (const float*)d_in[14];
    const float* ow = (const float*)d_in[15];
    const float* ob = (const float*)d_in[16];

    char* ws = (char*)d_ws;
    size_t off = 0;
    auto alloc = [&](size_t bytes) {
        size_t r = off;
        off += (bytes + 255) & ~(size_t)255;
        return r;
    };
    int* deg_i = (int*)(ws + alloc((size_t)NT * 4));
    int* cursor = (int*)(ws + alloc((size_t)NT * 4));
    int* rowst = (int*)(ws + alloc((size_t)NT * 4));
    float* degf = (float*)(ws + alloc((size_t)NT * 4));
    int* csr = (int*)(ws + alloc((size_t)E_TOT * 4));
    int* gidx = (int*)(ws + alloc((size_t)B * K * 4));
    float* t = (float*)(ws + alloc((size_t)NT * 32 * 4));
    float* hc1 = (float*)(ws + alloc((size_t)NT * 32 * 4));
    float* hc2 = (float*)(ws + alloc((size_t)NT * 32 * 4));
    float* hc3 = (float*)(ws + alloc((size_t)NT * 32 * 4));
    float* t4 = (float*)(ws + alloc((size_t)NT * 4));
    float* h4 = (float*)(ws + alloc((size_t)NT * 4));

    // deg_i and cursor are adjacent (NT*4 is 256-aligned): one memset clears both
    hipMemsetAsync(deg_i, 0, (size_t)NT * 4 * 2, stream);
    count_deg<<<(E_TOT + 255) / 256, 256, 0, stream>>>(edst, deg_i);
    scan_graph<<<B, 256, 0, stream>>>(deg_i, rowst, degf);
    scatter_edges<<<(E_TOT + 255) / 256, 256, 0, stream>>>(esrc, edst, rowst, cursor, csr);

    gemm_t<F_INN><<<NT / 128, 256, 0, stream>>>(node_feat, W1, t);
    agg32<false><<<NT / 8, 256, 0, stream>>>(t, csr, rowst, deg_i, degf, b1, nullptr, hc1, nullptr);
    gemm_t<32><<<NT / 128, 256, 0, stream>>>(hc1, W2, t);
    agg32<false><<<NT / 8, 256, 0, stream>>>(t, csr, rowst, deg_i, degf, b2, nullptr, hc2, nullptr);
    gemm_t<32><<<NT / 128, 256, 0, stream>>>(hc2, W3, t);
    agg32<true><<<NT / 8, 256, 0, stream>>>(t, csr, rowst, deg_i, degf, b3, W4, hc3, t4);
    agg1f<<<(NT + 255) / 256, 256, 0, stream>>>(t4, csr, rowst, deg_i, degf, b4, h4);

    sortpool<<<B, 256, 0, stream>>>(h4, gidx);
    head<<<B, 256, 0, stream>>>(hc1, hc2, hc3, h4, gidx, c1w, c1b, c2w, c2b, ow, ob, (float*)d_out);
}

// Round 4
// 233.352 us; speedup vs baseline: 3.5863x; 1.4442x over previous
//
#include <hip/hip_runtime.h>

constexpr int B = 64, N = 1500, NT = B * N;
constexpr int E_PER = 24000, E_TOT = B * E_PER;
constexpr int F_INN = 128, K = 30, TOT = 97;

// ---------------- Fused CSR build: one block per graph, CSR slice in LDS ------
__global__ __launch_bounds__(1024) void build_csr(const int* __restrict__ src, const int* __restrict__ dst,
                                                  int* __restrict__ csr, int* __restrict__ rowst,
                                                  int* __restrict__ degi, float* __restrict__ degf) {
    __shared__ int hist[N];       // counts -> cursors
    __shared__ int csr_l[E_PER];  // 96 KB CSR slice
    __shared__ int wsum[4];
    int g = blockIdx.x, t = threadIdx.x;
    int gbase = g * N;
    const int* dstg = dst + (size_t)g * E_PER;
    const int* srcg = src + (size_t)g * E_PER;

    for (int i = t; i < N; i += 1024) hist[i] = 0;
    __syncthreads();
    for (int e = t; e < E_PER; e += 1024)
        atomicAdd(&hist[dstg[e] - gbase], 1);
    __syncthreads();

    // prefix scan over 1500 counts (threads 0..255, 6 values each)
    int local[6];
    int sum = 0, x = 0;
    if (t < 256) {
#pragma unroll
        for (int i = 0; i < 6; ++i) {
            int v = t * 6 + i;
            int d = (v < N) ? hist[v] : 0;
            local[i] = d;
            sum += d;
        }
        x = sum;
        int lane = t & 63;
#pragma unroll
        for (int m = 1; m < 64; m <<= 1) {
            int y = __shfl_up(x, m, 64);
            if (lane >= m) x += y;
        }
        if (lane == 63) wsum[t >> 6] = x;
    }
    __syncthreads();
    if (t < 256) {
        int woff = 0;
        int wv = t >> 6;
        for (int w = 0; w < wv; ++w) woff += wsum[w];
        int run = x - sum + woff; // exclusive prefix of this thread's chunk
#pragma unroll
        for (int i = 0; i < 6; ++i) {
            int v = t * 6 + i;
            if (v < N) {
                rowst[gbase + v] = g * E_PER + run;
                degi[gbase + v] = local[i];
                degf[gbase + v] = (float)(local[i] + 1);
                hist[v] = run; // becomes scatter cursor
                run += local[i];
            }
        }
    }
    __syncthreads();
    for (int e = t; e < E_PER; e += 1024) {
        int d = dstg[e] - gbase;
        int pos = atomicAdd(&hist[d], 1);
        csr_l[pos] = srcg[e];
    }
    __syncthreads();
    for (int i = t; i < E_PER; i += 1024)
        csr[(size_t)g * E_PER + i] = csr_l[i];
}

// ---------------- Tiled GEMM: t[NT,32] = h[NT,KDIM] @ W[KDIM,32] ----------------
// 128 nodes per block; wave w owns output cols [8w,8w+8); lane owns nodes {2l, 2l+1}.
template <int KDIM>
__global__ __launch_bounds__(256) void gemm_t(const float* __restrict__ h,
                                              const float* __restrict__ W,
                                              float* __restrict__ t) {
    __shared__ float hs[32][128]; // [k][node] transposed chunk
    __shared__ float Ws[32][32];  // [k][out] chunk
    int tid = threadIdx.x;
    int wv = tid >> 6, lane = tid & 63;
    int v0 = blockIdx.x * 128;
    int og = wv * 8;
    float acc[2][8];
#pragma unroll
    for (int i = 0; i < 2; ++i)
#pragma unroll
        for (int j = 0; j < 8; ++j) acc[i][j] = 0.f;

    for (int kc = 0; kc < KDIM; kc += 32) {
        __syncthreads();
        { // stage h chunk transposed
            int n = tid >> 1, kh = (tid & 1) * 16;
            const float* hp = h + (size_t)(v0 + n) * KDIM + kc + kh;
            const float4* hp4 = reinterpret_cast<const float4*>(hp);
            float4 a = hp4[0], b = hp4[1], c = hp4[2], d = hp4[3];
            hs[kh + 0][n] = a.x;  hs[kh + 1][n] = a.y;  hs[kh + 2][n] = a.z;  hs[kh + 3][n] = a.w;
            hs[kh + 4][n] = b.x;  hs[kh + 5][n] = b.y;  hs[kh + 6][n] = b.z;  hs[kh + 7][n] = b.w;
            hs[kh + 8][n] = c.x;  hs[kh + 9][n] = c.y;  hs[kh + 10][n] = c.z; hs[kh + 11][n] = c.w;
            hs[kh + 12][n] = d.x; hs[kh + 13][n] = d.y; hs[kh + 14][n] = d.z; hs[kh + 15][n] = d.w;
        }
        { // stage W chunk
            int r = tid >> 3, c4 = (tid & 7) * 4;
            float4 w = *reinterpret_cast<const float4*>(W + (size_t)(kc + r) * 32 + c4);
            *reinterpret_cast<float4*>(&Ws[r][c4]) = w;
        }
        __syncthreads();
#pragma unroll
        for (int k = 0; k < 32; ++k) {
            float2 hv = *reinterpret_cast<const float2*>(&hs[k][2 * lane]);
            float4 w0 = *reinterpret_cast<const float4*>(&Ws[k][og]);
            float4 w1 = *reinterpret_cast<const float4*>(&Ws[k][og + 4]);
            acc[0][0] += hv.x * w0.x; acc[0][1] += hv.x * w0.y; acc[0][2] += hv.x * w0.z; acc[0][3] += hv.x * w0.w;
            acc[0][4] += hv.x * w1.x; acc[0][5] += hv.x * w1.y; acc[0][6] += hv.x * w1.z; acc[0][7] += hv.x * w1.w;
            acc[1][0] += hv.y * w0.x; acc[1][1] += hv.y * w0.y; acc[1][2] += hv.y * w0.z; acc[1][3] += hv.y * w0.w;
            acc[1][4] += hv.y * w1.x; acc[1][5] += hv.y * w1.y; acc[1][6] += hv.y * w1.z; acc[1][7] += hv.y * w1.w;
        }
    }
#pragma unroll
    for (int i = 0; i < 2; ++i) {
        float* op = t + (size_t)(v0 + 2 * lane + i) * 32 + og;
        float4 r0 = {acc[i][0], acc[i][1], acc[i][2], acc[i][3]};
        float4 r1 = {acc[i][4], acc[i][5], acc[i][6], acc[i][7]};
        reinterpret_cast<float4*>(op)[0] = r0;
        reinterpret_cast<float4*>(op)[1] = r1;
    }
}

// ---------------- Aggregate 32-wide: hout = tanh((gather(t)+t_self+b)/deg) ------
template <bool DO_T4>
__global__ __launch_bounds__(256) void agg32(const float* __restrict__ t,
                                             const int* __restrict__ csr, const int* __restrict__ rowst,
                                             const int* __restrict__ degi, const float* __restrict__ degf,
                                             const float* __restrict__ bias, const float* __restrict__ W4,
                                             float* __restrict__ hout, float* __restrict__ t4) {
    int v = blockIdx.x * 8 + (threadIdx.x >> 5);
    int f = threadIdx.x & 31;
    const float* tp = t + f;
    float acc = tp[(size_t)v * 32];
    int e0 = rowst[v], dc = degi[v];
    float a0 = 0.f, a1 = 0.f, a2 = 0.f, a3 = 0.f;
    int e = 0;
    for (; e + 4 <= dc; e += 4) {
        int s0 = csr[e0 + e], s1 = csr[e0 + e + 1], s2 = csr[e0 + e + 2], s3 = csr[e0 + e + 3];
        a0 += tp[(size_t)s0 * 32];
        a1 += tp[(size_t)s1 * 32];
        a2 += tp[(size_t)s2 * 32];
        a3 += tp[(size_t)s3 * 32];
    }
    for (; e < dc; ++e) a0 += tp[(size_t)csr[e0 + e] * 32];
    acc += (a0 + a1) + (a2 + a3);
    float out = tanhf((acc + bias[f]) / degf[v]);
    hout[(size_t)v * 32 + f] = out;
    if (DO_T4) {
        float p = out * W4[f];
#pragma unroll
        for (int m = 16; m >= 1; m >>= 1) p += __shfl_xor(p, m, 64);
        if (f == 0) t4[v] = p;
    }
}

// ---------------- Layer-4 aggregate: scalar gather ----------------
__global__ __launch_bounds__(256) void agg1f(const float* __restrict__ t4,
                                             const int* __restrict__ csr, const int* __restrict__ rowst,
                                             const int* __restrict__ degi, const float* __restrict__ degf,
                                             const float* __restrict__ b4, float* __restrict__ h4) {
    int v = blockIdx.x * 256 + threadIdx.x;
    if (v >= NT) return;
    float acc = t4[v];
    int e0 = rowst[v], dc = degi[v];
    float a0 = 0.f, a1 = 0.f, a2 = 0.f, a3 = 0.f;
    int e = 0;
    for (; e + 4 <= dc; e += 4) {
        a0 += t4[csr[e0 + e]];
        a1 += t4[csr[e0 + e + 1]];
        a2 += t4[csr[e0 + e + 2]];
        a3 += t4[csr[e0 + e + 3]];
    }
    for (; e < dc; ++e) a0 += t4[csr[e0 + e]];
    acc += (a0 + a1) + (a2 + a3);
    h4[v] = tanhf((acc + b4[0]) / degf[v]);
}

// ---------------- Fused sortpool + head: one block per graph ----------------
__global__ __launch_bounds__(256) void sort_head(const float* __restrict__ hc1, const float* __restrict__ hc2,
                                                 const float* __restrict__ hc3, const float* __restrict__ h4,
                                                 const float* __restrict__ c1w, const float* __restrict__ c1b,
                                                 const float* __restrict__ c2w, const float* __restrict__ c2b,
                                                 const float* __restrict__ ow, const float* __restrict__ ob,
                                                 float* __restrict__ out) {
    __shared__ float vals[N];
    __shared__ int topk[K];
    __shared__ float wvv[4];
    __shared__ int wii[4];
    __shared__ float pooled[K][TOT];
    __shared__ float c1[16][K];
    __shared__ float mp[16][16];
    __shared__ float dense[352];
    int g = blockIdx.x, t = threadIdx.x;
    int lane = t & 63, wave = t >> 6;

    for (int v = t; v < N; v += 256) vals[v] = h4[g * N + v];
    __syncthreads();
    for (int k = 0; k < K; ++k) {
        float bv = -1e30f;
        int bi = N;
        for (int v = t; v < N; v += 256) {
            float x = vals[v];
            if (x > bv) { bv = x; bi = v; }
        }
#pragma unroll
        for (int m = 32; m >= 1; m >>= 1) {
            float ov = __shfl_xor(bv, m, 64);
            int oi = __shfl_xor(bi, m, 64);
            if (ov > bv || (ov == bv && oi < bi)) { bv = ov; bi = oi; }
        }
        if (lane == 0) { wvv[wave] = bv; wii[wave] = bi; }
        __syncthreads();
        if (t == 0) {
            float b0 = wvv[0];
            int i0 = wii[0];
            for (int w = 1; w < 4; ++w)
                if (wvv[w] > b0 || (wvv[w] == b0 && wii[w] < i0)) { b0 = wvv[w]; i0 = wii[w]; }
            topk[k] = g * N + i0;
            vals[i0] = -1e30f;
        }
        __syncthreads();
    }

    for (int i = t; i < K * TOT; i += 256) {
        int k = i / TOT, d = i % TOT;
        int gi = topk[k];
        float val = (d < 32) ? hc1[(size_t)gi * 32 + d]
                  : (d < 64) ? hc2[(size_t)gi * 32 + d - 32]
                  : (d < 96) ? hc3[(size_t)gi * 32 + d - 64]
                             : h4[gi];
        pooled[k][d] = val;
    }
    __syncthreads();
    for (int i = t; i < 16 * K; i += 256) {
        int o = i / K, k = i % K;
        float s = c1b[o];
        for (int d = 0; d < TOT; ++d) s += pooled[k][d] * c1w[o * TOT + d];
        c1[o][k] = fmaxf(s, 0.f);
    }
    __syncthreads();
    for (int i = t; i < 16 * 15; i += 256) {
        int o = i / 15, p = i % 15;
        mp[o][p] = fmaxf(c1[o][2 * p], c1[o][2 * p + 1]);
    }
    __syncthreads();
    for (int i = t; i < 352; i += 256) {
        int o = i / 11, p = i % 11;
        float s = c2b[o];
#pragma unroll
        for (int ci = 0; ci < 16; ++ci)
#pragma unroll
            for (int tt = 0; tt < 5; ++tt)
                s += mp[ci][p + tt] * c2w[(o * 16 + ci) * 5 + tt];
        dense[i] = fmaxf(s, 0.f);
    }
    __syncthreads();
    if (t < 128) {
        float s = ob[t];
        for (int m = 0; m < 352; ++m) s += dense[m] * ow[m * 128 + t];
        out[g * 128 + t] = fmaxf(s, 0.f);
    }
}

extern "C" void kernel_launch(void* const* d_in, const int* in_sizes, int n_in,
                              void* d_out, int out_size, void* d_ws, size_t ws_size,
                              hipStream_t stream) {
    const float* node_feat = (const float*)d_in[0];
    const int* esrc = (const int*)d_in[1];
    const int* edst = (const int*)d_in[2];
    const float* W1 = (const float*)d_in[3];
    const float* b1 = (const float*)d_in[4];
    const float* W2 = (const float*)d_in[5];
    const float* b2 = (const float*)d_in[6];
    const float* W3 = (const float*)d_in[7];
    const float* b3 = (const float*)d_in[8];
    const float* W4 = (const float*)d_in[9];
    const float* b4 = (const float*)d_in[10];
    const float* c1w = (const float*)d_in[11];
    const float* c1b = (const float*)d_in[12];
    const float* c2w = (const float*)d_in[13];
    const float* c2b = (const float*)d_in[14];
    const float* ow = (const float*)d_in[15];
    const float* ob = (const float*)d_in[16];

    char* ws = (char*)d_ws;
    size_t off = 0;
    auto alloc = [&](size_t bytes) {
        size_t r = off;
        off += (bytes + 255) & ~(size_t)255;
        return r;
    };
    int* deg_i = (int*)(ws + alloc((size_t)NT * 4));
    int* rowst = (int*)(ws + alloc((size_t)NT * 4));
    float* degf = (float*)(ws + alloc((size_t)NT * 4));
    int* csr = (int*)(ws + alloc((size_t)E_TOT * 4));
    float* t = (float*)(ws + alloc((size_t)NT * 32 * 4));
    float* hc1 = (float*)(ws + alloc((size_t)NT * 32 * 4));
    float* hc2 = (float*)(ws + alloc((size_t)NT * 32 * 4));
    float* hc3 = (float*)(ws + alloc((size_t)NT * 32 * 4));
    float* t4 = (float*)(ws + alloc((size_t)NT * 4));
    float* h4 = (float*)(ws + alloc((size_t)NT * 4));

    build_csr<<<B, 1024, 0, stream>>>(esrc, edst, csr, rowst, deg_i, degf);

    gemm_t<F_INN><<<NT / 128, 256, 0, stream>>>(node_feat, W1, t);
    agg32<false><<<NT / 8, 256, 0, stream>>>(t, csr, rowst, deg_i, degf, b1, nullptr, hc1, nullptr);
    gemm_t<32><<<NT / 128, 256, 0, stream>>>(hc1, W2, t);
    agg32<false><<<NT / 8, 256, 0, stream>>>(t, csr, rowst, deg_i, degf, b2, nullptr, hc2, nullptr);
    gemm_t<32><<<NT / 128, 256, 0, stream>>>(hc2, W3, t);
    agg32<true><<<NT / 8, 256, 0, stream>>>(t, csr, rowst, deg_i, degf, b3, W4, hc3, t4);
    agg1f<<<(NT + 255) / 256, 256, 0, stream>>>(t4, csr, rowst, deg_i, degf, b4, h4);

    sort_head<<<B, 256, 0, stream>>>(hc1, hc2, hc3, h4, c1w, c1b, c2w, c2b, ow, ob, (float*)d_out);
}

// Round 5
// 215.801 us; speedup vs baseline: 3.8779x; 1.0813x over previous
//
#include <hip/hip_runtime.h>

constexpr int B = 64, N = 1500, NT = B * N;
constexpr int E_PER = 24000, E_TOT = B * E_PER;
constexpr int F_INN = 128, K = 30, TOT = 97;

// ---------------- Fused CSR build: one block per graph, CSR slice in LDS ------
__global__ __launch_bounds__(1024) void build_csr(const int* __restrict__ src, const int* __restrict__ dst,
                                                  int* __restrict__ csr, int* __restrict__ rowst,
                                                  int* __restrict__ degi, float* __restrict__ degf) {
    __shared__ int hist[N];       // counts -> cursors
    __shared__ int csr_l[E_PER];  // 96 KB CSR slice
    __shared__ int wsum[4];
    int g = blockIdx.x, t = threadIdx.x;
    int gbase = g * N;
    const int* dstg = dst + (size_t)g * E_PER;
    const int* srcg = src + (size_t)g * E_PER;

    for (int i = t; i < N; i += 1024) hist[i] = 0;
    __syncthreads();
    for (int e = t; e < E_PER; e += 1024)
        atomicAdd(&hist[dstg[e] - gbase], 1);
    __syncthreads();

    // prefix scan over 1500 counts (threads 0..255, 6 values each)
    int local[6];
    int sum = 0, x = 0;
    if (t < 256) {
#pragma unroll
        for (int i = 0; i < 6; ++i) {
            int v = t * 6 + i;
            int d = (v < N) ? hist[v] : 0;
            local[i] = d;
            sum += d;
        }
        x = sum;
        int lane = t & 63;
#pragma unroll
        for (int m = 1; m < 64; m <<= 1) {
            int y = __shfl_up(x, m, 64);
            if (lane >= m) x += y;
        }
        if (lane == 63) wsum[t >> 6] = x;
    }
    __syncthreads();
    if (t < 256) {
        int woff = 0;
        int wv = t >> 6;
        for (int w = 0; w < wv; ++w) woff += wsum[w];
        int run = x - sum + woff; // exclusive prefix of this thread's chunk
#pragma unroll
        for (int i = 0; i < 6; ++i) {
            int v = t * 6 + i;
            if (v < N) {
                rowst[gbase + v] = g * E_PER + run;
                degi[gbase + v] = local[i];
                degf[gbase + v] = (float)(local[i] + 1);
                hist[v] = run; // becomes scatter cursor
                run += local[i];
            }
        }
    }
    __syncthreads();
    for (int e = t; e < E_PER; e += 1024) {
        int d = dstg[e] - gbase;
        int pos = atomicAdd(&hist[d], 1);
        csr_l[pos] = srcg[e];
    }
    __syncthreads();
    for (int i = t; i < E_PER; i += 1024)
        csr[(size_t)g * E_PER + i] = csr_l[i];
}

// ---------------- Tiled GEMM: t[NT,32] = h[NT,128] @ W[128,32] ----------------
template <int KDIM>
__global__ __launch_bounds__(256) void gemm_t(const float* __restrict__ h,
                                              const float* __restrict__ W,
                                              float* __restrict__ t) {
    __shared__ float hs[32][128];
    __shared__ float Ws[32][32];
    int tid = threadIdx.x;
    int wv = tid >> 6, lane = tid & 63;
    int v0 = blockIdx.x * 128;
    int og = wv * 8;
    float acc[2][8];
#pragma unroll
    for (int i = 0; i < 2; ++i)
#pragma unroll
        for (int j = 0; j < 8; ++j) acc[i][j] = 0.f;

    for (int kc = 0; kc < KDIM; kc += 32) {
        __syncthreads();
        {
            int n = tid >> 1, kh = (tid & 1) * 16;
            const float* hp = h + (size_t)(v0 + n) * KDIM + kc + kh;
            const float4* hp4 = reinterpret_cast<const float4*>(hp);
            float4 a = hp4[0], b = hp4[1], c = hp4[2], d = hp4[3];
            hs[kh + 0][n] = a.x;  hs[kh + 1][n] = a.y;  hs[kh + 2][n] = a.z;  hs[kh + 3][n] = a.w;
            hs[kh + 4][n] = b.x;  hs[kh + 5][n] = b.y;  hs[kh + 6][n] = b.z;  hs[kh + 7][n] = b.w;
            hs[kh + 8][n] = c.x;  hs[kh + 9][n] = c.y;  hs[kh + 10][n] = c.z; hs[kh + 11][n] = c.w;
            hs[kh + 12][n] = d.x; hs[kh + 13][n] = d.y; hs[kh + 14][n] = d.z; hs[kh + 15][n] = d.w;
        }
        {
            int r = tid >> 3, c4 = (tid & 7) * 4;
            float4 w = *reinterpret_cast<const float4*>(W + (size_t)(kc + r) * 32 + c4);
            *reinterpret_cast<float4*>(&Ws[r][c4]) = w;
        }
        __syncthreads();
#pragma unroll
        for (int k = 0; k < 32; ++k) {
            float2 hv = *reinterpret_cast<const float2*>(&hs[k][2 * lane]);
            float4 w0 = *reinterpret_cast<const float4*>(&Ws[k][og]);
            float4 w1 = *reinterpret_cast<const float4*>(&Ws[k][og + 4]);
            acc[0][0] += hv.x * w0.x; acc[0][1] += hv.x * w0.y; acc[0][2] += hv.x * w0.z; acc[0][3] += hv.x * w0.w;
            acc[0][4] += hv.x * w1.x; acc[0][5] += hv.x * w1.y; acc[0][6] += hv.x * w1.z; acc[0][7] += hv.x * w1.w;
            acc[1][0] += hv.y * w0.x; acc[1][1] += hv.y * w0.y; acc[1][2] += hv.y * w0.z; acc[1][3] += hv.y * w0.w;
            acc[1][4] += hv.y * w1.x; acc[1][5] += hv.y * w1.y; acc[1][6] += hv.y * w1.z; acc[1][7] += hv.y * w1.w;
        }
    }
#pragma unroll
    for (int i = 0; i < 2; ++i) {
        float* op = t + (size_t)(v0 + 2 * lane + i) * 32 + og;
        float4 r0 = {acc[i][0], acc[i][1], acc[i][2], acc[i][3]};
        float4 r1 = {acc[i][4], acc[i][5], acc[i][6], acc[i][7]};
        reinterpret_cast<float4*>(op)[0] = r0;
        reinterpret_cast<float4*>(op)[1] = r1;
    }
}

// ---- Aggregate 32-wide + fused next-layer transform epilogue ----
// hout = tanh((gather(t)+t_self+b)/deg); FUSE=32: tn = hout@Wn; FUSE=1: tn = hout.Wn
template <int FUSE>
__global__ __launch_bounds__(256) void agg_f(const float* __restrict__ t,
                                             const int* __restrict__ csr, const int* __restrict__ rowst,
                                             const int* __restrict__ degi, const float* __restrict__ degf,
                                             const float* __restrict__ bias, const float* __restrict__ Wn,
                                             float* __restrict__ hout, float* __restrict__ tn) {
    __shared__ float Ws[1024];
    __shared__ float outs[8][32];
    if (FUSE == 32) {
        for (int i = threadIdx.x; i < 1024; i += 256) Ws[i] = Wn[i];
    }
    int hw = threadIdx.x >> 5;
    int v = blockIdx.x * 8 + hw;
    int f = threadIdx.x & 31;
    const float* tp = t + f;
    float acc = tp[(size_t)v * 32];
    int e0 = rowst[v], dc = degi[v];
    float a0 = 0.f, a1 = 0.f, a2 = 0.f, a3 = 0.f;
    int e = 0;
    for (; e + 4 <= dc; e += 4) {
        int s0 = csr[e0 + e], s1 = csr[e0 + e + 1], s2 = csr[e0 + e + 2], s3 = csr[e0 + e + 3];
        a0 += tp[(size_t)s0 * 32];
        a1 += tp[(size_t)s1 * 32];
        a2 += tp[(size_t)s2 * 32];
        a3 += tp[(size_t)s3 * 32];
    }
    for (; e < dc; ++e) a0 += tp[(size_t)csr[e0 + e] * 32];
    acc += (a0 + a1) + (a2 + a3);
    float out = tanhf((acc + bias[f]) / degf[v]);
    hout[(size_t)v * 32 + f] = out;
    if (FUSE == 32) {
        outs[hw][f] = out;
        __syncthreads();
        float s = 0.f;
#pragma unroll
        for (int ff = 0; ff < 32; ++ff) s += outs[hw][ff] * Ws[ff * 32 + f];
        tn[(size_t)v * 32 + f] = s;
    } else {
        float p = out * Wn[f];
#pragma unroll
        for (int m = 16; m >= 1; m >>= 1) p += __shfl_xor(p, m, 64);
        if (f == 0) tn[v] = p;
    }
}

// ---------------- Layer-4 aggregate: scalar gather ----------------
__global__ __launch_bounds__(256) void agg1f(const float* __restrict__ t4,
                                             const int* __restrict__ csr, const int* __restrict__ rowst,
                                             const int* __restrict__ degi, const float* __restrict__ degf,
                                             const float* __restrict__ b4, float* __restrict__ h4) {
    int v = blockIdx.x * 256 + threadIdx.x;
    if (v >= NT) return;
    float acc = t4[v];
    int e0 = rowst[v], dc = degi[v];
    float a0 = 0.f, a1 = 0.f, a2 = 0.f, a3 = 0.f;
    int e = 0;
    for (; e + 4 <= dc; e += 4) {
        a0 += t4[csr[e0 + e]];
        a1 += t4[csr[e0 + e + 1]];
        a2 += t4[csr[e0 + e + 2]];
        a3 += t4[csr[e0 + e + 3]];
    }
    for (; e < dc; ++e) a0 += t4[csr[e0 + e]];
    acc += (a0 + a1) + (a2 + a3);
    h4[v] = tanhf((acc + b4[0]) / degf[v]);
}

// ---------------- Fused sortpool + head: one block per graph ----------------
// top-K via register-resident uint64 keys: (sortable(val)<<32)|(0x7FFFFFFF-idx)
__global__ __launch_bounds__(256) void sort_head(const float* __restrict__ hc1, const float* __restrict__ hc2,
                                                 const float* __restrict__ hc3, const float* __restrict__ h4,
                                                 const float* __restrict__ c1w, const float* __restrict__ c1b,
                                                 const float* __restrict__ c2w, const float* __restrict__ c2b,
                                                 const float* __restrict__ ow, const float* __restrict__ ob,
                                                 float* __restrict__ out) {
    __shared__ unsigned long long wavetop[4][K];
    __shared__ int topk[K];
    __shared__ float pooled[K][TOT];
    __shared__ float c1[16][K];
    __shared__ float mp[16][16];
    __shared__ float dense[352];
    int g = blockIdx.x, t = threadIdx.x;
    int lane = t & 63, w = t >> 6;

    // wave-local top-K over 375 elements held in 6 regs/lane (no barriers)
    unsigned long long key[6];
    const float* hp = h4 + (size_t)g * N + w * 375;
#pragma unroll
    for (int i = 0; i < 6; ++i) {
        int li = i * 64 + lane;
        unsigned long long kk = 0ull;
        if (li < 375) {
            unsigned int b = __float_as_uint(hp[li]);
            unsigned int sk = (b & 0x80000000u) ? ~b : (b | 0x80000000u);
            kk = ((unsigned long long)sk << 32) | (unsigned int)(0x7FFFFFFF - (w * 375 + li));
        }
        key[i] = kk;
    }
    for (int k = 0; k < K; ++k) {
        unsigned long long m = key[0];
#pragma unroll
        for (int i = 1; i < 6; ++i) m = (key[i] > m) ? key[i] : m;
#pragma unroll
        for (int d = 32; d >= 1; d >>= 1) {
            unsigned long long o = __shfl_xor(m, d, 64);
            m = (o > m) ? o : m;
        }
#pragma unroll
        for (int i = 0; i < 6; ++i)
            if (key[i] == m) key[i] = 0ull;
        if (lane == 0) wavetop[w][k] = m;
    }
    __syncthreads();
    // merge 4x30 candidates on wave 0
    if (w == 0) {
        int i0 = lane, i1 = lane + 64;
        unsigned long long c0 = (i0 < 4 * K) ? wavetop[i0 / K][i0 % K] : 0ull;
        unsigned long long c1v = (i1 < 4 * K) ? wavetop[i1 / K][i1 % K] : 0ull;
        for (int k = 0; k < K; ++k) {
            unsigned long long m = (c0 > c1v) ? c0 : c1v;
#pragma unroll
            for (int d = 32; d >= 1; d >>= 1) {
                unsigned long long o = __shfl_xor(m, d, 64);
                m = (o > m) ? o : m;
            }
            if (c0 == m) c0 = 0ull;
            if (c1v == m) c1v = 0ull;
            if (lane == 0)
                topk[k] = g * N + (0x7FFFFFFF - (int)(unsigned int)(m & 0xFFFFFFFFu));
        }
    }
    __syncthreads();

    for (int i = t; i < K * TOT; i += 256) {
        int k = i / TOT, d = i % TOT;
        int gi = topk[k];
        float val = (d < 32) ? hc1[(size_t)gi * 32 + d]
                  : (d < 64) ? hc2[(size_t)gi * 32 + d - 32]
                  : (d < 96) ? hc3[(size_t)gi * 32 + d - 64]
                             : h4[gi];
        pooled[k][d] = val;
    }
    __syncthreads();
    for (int i = t; i < 16 * K; i += 256) {
        int o = i / K, k = i % K;
        float s = c1b[o];
        for (int d = 0; d < TOT; ++d) s += pooled[k][d] * c1w[o * TOT + d];
        c1[o][k] = fmaxf(s, 0.f);
    }
    __syncthreads();
    for (int i = t; i < 16 * 15; i += 256) {
        int o = i / 15, p = i % 15;
        mp[o][p] = fmaxf(c1[o][2 * p], c1[o][2 * p + 1]);
    }
    __syncthreads();
    for (int i = t; i < 352; i += 256) {
        int o = i / 11, p = i % 11;
        float s = c2b[o];
#pragma unroll
        for (int ci = 0; ci < 16; ++ci)
#pragma unroll
            for (int tt = 0; tt < 5; ++tt)
                s += mp[ci][p + tt] * c2w[(o * 16 + ci) * 5 + tt];
        dense[i] = fmaxf(s, 0.f);
    }
    __syncthreads();
    if (t < 128) {
        float s = ob[t];
        for (int m = 0; m < 352; ++m) s += dense[m] * ow[m * 128 + t];
        out[g * 128 + t] = fmaxf(s, 0.f);
    }
}

extern "C" void kernel_launch(void* const* d_in, const int* in_sizes, int n_in,
                              void* d_out, int out_size, void* d_ws, size_t ws_size,
                              hipStream_t stream) {
    const float* node_feat = (const float*)d_in[0];
    const int* esrc = (const int*)d_in[1];
    const int* edst = (const int*)d_in[2];
    const float* W1 = (const float*)d_in[3];
    const float* b1 = (const float*)d_in[4];
    const float* W2 = (const float*)d_in[5];
    const float* b2 = (const float*)d_in[6];
    const float* W3 = (const float*)d_in[7];
    const float* b3 = (const float*)d_in[8];
    const float* W4 = (const float*)d_in[9];
    const float* b4 = (const float*)d_in[10];
    const float* c1w = (const float*)d_in[11];
    const float* c1b = (const float*)d_in[12];
    const float* c2w = (const float*)d_in[13];
    const float* c2b = (const float*)d_in[14];
    const float* ow = (const float*)d_in[15];
    const float* ob = (const float*)d_in[16];

    char* ws = (char*)d_ws;
    size_t off = 0;
    auto alloc = [&](size_t bytes) {
        size_t r = off;
        off += (bytes + 255) & ~(size_t)255;
        return r;
    };
    int* deg_i = (int*)(ws + alloc((size_t)NT * 4));
    int* rowst = (int*)(ws + alloc((size_t)NT * 4));
    float* degf = (float*)(ws + alloc((size_t)NT * 4));
    int* csr = (int*)(ws + alloc((size_t)E_TOT * 4));
    float* tA = (float*)(ws + alloc((size_t)NT * 32 * 4));
    float* tB = (float*)(ws + alloc((size_t)NT * 32 * 4));
    float* hc1 = (float*)(ws + alloc((size_t)NT * 32 * 4));
    float* hc2 = (float*)(ws + alloc((size_t)NT * 32 * 4));
    float* hc3 = (float*)(ws + alloc((size_t)NT * 32 * 4));
    float* t4 = (float*)(ws + alloc((size_t)NT * 4));
    float* h4 = (float*)(ws + alloc((size_t)NT * 4));

    build_csr<<<B, 1024, 0, stream>>>(esrc, edst, csr, rowst, deg_i, degf);

    gemm_t<F_INN><<<NT / 128, 256, 0, stream>>>(node_feat, W1, tA);
    agg_f<32><<<NT / 8, 256, 0, stream>>>(tA, csr, rowst, deg_i, degf, b1, W2, hc1, tB);
    agg_f<32><<<NT / 8, 256, 0, stream>>>(tB, csr, rowst, deg_i, degf, b2, W3, hc2, tA);
    agg_f<1><<<NT / 8, 256, 0, stream>>>(tA, csr, rowst, deg_i, degf, b3, W4, hc3, t4);
    agg1f<<<(NT + 255) / 256, 256, 0, stream>>>(t4, csr, rowst, deg_i, degf, b4, h4);

    sort_head<<<B, 256, 0, stream>>>(hc1, hc2, hc3, h4, c1w, c1b, c2w, c2b, ow, ob, (float*)d_out);
}